// Round 1
// baseline (318.223 us; speedup 1.0000x reference)
//
#include <hip/hip_runtime.h>
#include <hip/hip_bf16.h>

// Problem constants (fixed by reference file)
#define EMBED    256
#define HEADS    8
#define LEVELS   4
#define POINTS   4
#define HEAD_DIM 32
#define BS       8
#define NQ       900
#define NV       13294          // 100*100 + 50*50 + 25*25 + 13*13
#define MV       (BS*NV)        // 106352 rows of the value GEMM
#define MQ       (BS*NQ)        // 7200 rows of the query GEMMs
#define NQOUT    384            // 256 offset cols + 128 attn cols

typedef float  f32x4  __attribute__((ext_vector_type(4)));
typedef __bf16 bf16x8 __attribute__((ext_vector_type(8)));
typedef unsigned short ushort8 __attribute__((ext_vector_type(8)));

__device__ __forceinline__ unsigned short f2bf(float f) {
    unsigned u = __builtin_bit_cast(unsigned, f);
    u += 0x7FFFu + ((u >> 16) & 1u);          // RNE
    return (unsigned short)(u >> 16);
}
__device__ __forceinline__ float bf2f(unsigned short h) {
    unsigned u = ((unsigned)h) << 16;
    return __builtin_bit_cast(float, u);
}

// ---------------------------------------------------------------------------
// Prep: transpose + cast weights to bf16 (B^T layout: [n][k], k contiguous)
//   WtV: 256x256 from W_v (K x N) ;  WtO: 256x256 from W_out
//   WtQ: 384x256 -- rows 0..255 from W_off, rows 256..383 from W_attn
//   biasQ: 384 = b_off ++ b_attn
// ---------------------------------------------------------------------------
__global__ __launch_bounds__(256) void prep_kernel(
    const float* __restrict__ Wv,  const float* __restrict__ Woff,
    const float* __restrict__ Wattn, const float* __restrict__ Wout,
    const float* __restrict__ boff, const float* __restrict__ battn,
    unsigned short* __restrict__ WtV, unsigned short* __restrict__ WtQ,
    unsigned short* __restrict__ WtO, float* __restrict__ biasQ)
{
    int n = blockIdx.x;      // 0..383
    int k = threadIdx.x;     // 0..255
    if (n < 256) {
        WtV[n * 256 + k] = f2bf(Wv [k * 256 + n]);
        WtO[n * 256 + k] = f2bf(Wout[k * 256 + n]);
        WtQ[n * 256 + k] = f2bf(Woff[k * 256 + n]);
    } else {
        int j = n - 256;
        WtQ[n * 256 + k] = f2bf(Wattn[k * 128 + j]);
    }
    if (k == 0) biasQ[n] = (n < 256) ? boff[n] : battn[n - 256];
}

// ---------------------------------------------------------------------------
// MFMA bf16 GEMM:  C[M x N] = A[M x K](fp32) * Bt[N x K](bf16)^T + bias (+Id)
// Block = 256 threads (4 waves), tile BM x BN, BK=32, each wave = 64x64
// via 4x4 mfma_f32_16x16x32_bf16. K multiple of 32, N multiple of BN.
// ---------------------------------------------------------------------------
template <int WGM, int WGN, bool OUT_BF16, bool ADD_ID>
__global__ __launch_bounds__(256) void gemm_kernel(
    const float* __restrict__ A, const unsigned short* __restrict__ Bt,
    const float* __restrict__ bias, const float* __restrict__ Ident,
    void* __restrict__ C, int M, int K, int Ntot)
{
    constexpr int BM = WGM * 64, BN = WGN * 64, BK = 32;
    constexpr int LDK = 40;                       // padded LDS stride (bf16)
    __shared__ unsigned short As[BM * LDK];
    __shared__ unsigned short Bs[BN * LDK];

    const int tid  = threadIdx.x;
    const int wave = tid >> 6, lane = tid & 63;
    const int wm = wave / WGN, wn = wave % WGN;
    const int m0 = blockIdx.x * BM;
    const int n0 = blockIdx.y * BN;
    const int lrow = lane & 15;                   // fragment row index
    const int kq   = lane >> 4;                   // quad -> k base = kq*8

    f32x4 acc[4][4] = {};

    for (int kk = 0; kk < K; kk += BK) {
        // ---- stage A (fp32 -> bf16), 8 floats per thread-chunk ----
        #pragma unroll
        for (int c = 0; c < (BM * BK) / (256 * 8); ++c) {
            int flat = (c * 256 + tid) * 8;
            int row = flat >> 5, k0 = flat & 31;
            int gr = m0 + row;
            ushort8 w;
            if (gr < M) {
                const float* src = A + (size_t)gr * K + kk + k0;
                f32x4 v0 = *(const f32x4*)(src);
                f32x4 v1 = *(const f32x4*)(src + 4);
                #pragma unroll
                for (int e = 0; e < 4; ++e) { w[e] = f2bf(v0[e]); w[4+e] = f2bf(v1[e]); }
            } else {
                w = (ushort8)0;
            }
            *(ushort8*)&As[row * LDK + k0] = w;
        }
        // ---- stage B (bf16 copy) ----
        #pragma unroll
        for (int c = 0; c < (BN * BK) / (256 * 8); ++c) {
            int flat = (c * 256 + tid) * 8;
            int row = flat >> 5, k0 = flat & 31;
            ushort8 w = *(const ushort8*)(Bt + (size_t)(n0 + row) * K + kk + k0);
            *(ushort8*)&Bs[row * LDK + k0] = w;
        }
        __syncthreads();

        bf16x8 afrag[4], bfrag[4];
        #pragma unroll
        for (int i = 0; i < 4; ++i)
            afrag[i] = *(const bf16x8*)&As[(wm * 64 + i * 16 + lrow) * LDK + kq * 8];
        #pragma unroll
        for (int j = 0; j < 4; ++j)
            bfrag[j] = *(const bf16x8*)&Bs[(wn * 64 + j * 16 + lrow) * LDK + kq * 8];
        #pragma unroll
        for (int i = 0; i < 4; ++i)
            #pragma unroll
            for (int j = 0; j < 4; ++j)
                acc[i][j] = __builtin_amdgcn_mfma_f32_16x16x32_bf16(
                    afrag[i], bfrag[j], acc[i][j], 0, 0, 0);
        __syncthreads();
    }

    // ---- epilogue: D row = kq*4 + reg, col = lrow ----
    #pragma unroll
    for (int i = 0; i < 4; ++i) {
        #pragma unroll
        for (int j = 0; j < 4; ++j) {
            int n = n0 + wn * 64 + j * 16 + lrow;
            float bn = bias[n];
            #pragma unroll
            for (int r = 0; r < 4; ++r) {
                int m = m0 + wm * 64 + i * 16 + kq * 4 + r;
                if (m < M) {
                    float val = acc[i][j][r] + bn;
                    if (ADD_ID) val += Ident[(size_t)m * Ntot + n];
                    if (OUT_BF16)
                        ((unsigned short*)C)[(size_t)m * Ntot + n] = f2bf(val);
                    else
                        ((float*)C)[(size_t)m * Ntot + n] = val;
                }
            }
        }
    }
}

// ---------------------------------------------------------------------------
// Sampling: 16 lanes per (b,q,h) triple; lane s (0..15) owns sample s=l*4+p.
// Softmax over 16 via width-16 shuffles; each lane then handles 2 channels.
// ---------------------------------------------------------------------------
__device__ const int   LVL_W[4]  = {100, 50, 25, 13};
__device__ const int   LVL_H[4]  = {100, 50, 25, 13};
__device__ const int   LVL_S[4]  = {0, 10000, 12500, 13125};

__global__ __launch_bounds__(256) void sample_kernel(
    const unsigned short* __restrict__ V,   // (BS*NV, 256) bf16
    const float* __restrict__ Qout,         // (BS*NQ, 384)
    const float* __restrict__ RP,           // (BS, NQ, 4, 2)
    float* __restrict__ OutS)               // (BS*NQ, 256)
{
    const int gid = blockIdx.x * 16 + (threadIdx.x >> 4);   // triple index
    const int s   = threadIdx.x & 15;                       // lane-in-group
    const int h   = gid & 7;
    const int bq  = gid >> 3;                               // b*NQ + q
    const int b   = bq / NQ;

    const float* qrow = Qout + (size_t)bq * NQOUT;

    // per-lane sample s precompute
    const int l = s >> 2;
    const float ox = qrow[h * 32 + 2 * s];
    const float oy = qrow[h * 32 + 2 * s + 1];
    float logit    = qrow[256 + h * 16 + s];
    const float rpx = RP[((size_t)bq * 4 + l) * 2 + 0];
    const float rpy = RP[((size_t)bq * 4 + l) * 2 + 1];
    int W = LVL_W[l], H = LVL_H[l], st = LVL_S[l];
    // loc*W - 0.5 with norm=(W,H):  x = rpx*W + ox - 0.5
    float x = rpx * (float)W + ox - 0.5f;
    float y = rpy * (float)H + oy - 0.5f;
    float fx = floorf(x), fy = floorf(y);
    float lx = x - fx, ly = y - fy;
    int ix = (int)fx, iy = (int)fy;

    // softmax over the 16 lanes of this group
    float mx = logit;
    #pragma unroll
    for (int o = 8; o; o >>= 1) mx = fmaxf(mx, __shfl_xor(mx, o, 16));
    float e = __expf(logit - mx);
    float sum = e;
    #pragma unroll
    for (int o = 8; o; o >>= 1) sum += __shfl_xor(sum, o, 16);
    const float wgt = e / sum;

    const unsigned short* vb = V + ((size_t)b * NV) * 256 + h * 32 + 2 * s;
    float ax = 0.f, ay = 0.f;

    #pragma unroll
    for (int sp = 0; sp < 16; ++sp) {
        float ws  = __shfl(wgt, sp, 16);
        float lxs = __shfl(lx,  sp, 16);
        float lys = __shfl(ly,  sp, 16);
        int  ixs  = __shfl(ix,  sp, 16);
        int  iys  = __shfl(iy,  sp, 16);
        int  Ws   = __shfl(W,   sp, 16);
        int  Hs   = __shfl(H,   sp, 16);
        int  sts  = __shfl(st,  sp, 16);
        #pragma unroll
        for (int corner = 0; corner < 4; ++corner) {
            int dx = corner & 1, dy = corner >> 1;
            int xi = ixs + dx, yi = iys + dy;
            float cw = ws * (dx ? lxs : 1.f - lxs) * (dy ? lys : 1.f - lys);
            if (xi >= 0 && xi < Ws && yi >= 0 && yi < Hs && cw != 0.f) {
                const unsigned short* p = vb + (size_t)(sts + yi * Ws + xi) * 256;
                unsigned pv = *(const unsigned*)p;       // 2 bf16
                ax += cw * bf2f((unsigned short)(pv & 0xFFFF));
                ay += cw * bf2f((unsigned short)(pv >> 16));
            }
        }
    }
    float2* o = (float2*)(OutS + (size_t)bq * 256 + h * 32);
    o[s] = make_float2(ax, ay);
}

// ---------------------------------------------------------------------------
extern "C" void kernel_launch(void* const* d_in, const int* in_sizes, int n_in,
                              void* d_out, int out_size, void* d_ws, size_t ws_size,
                              hipStream_t stream)
{
    const float* query  = (const float*)d_in[0];
    const float* value  = (const float*)d_in[1];
    const float* rp     = (const float*)d_in[2];
    // d_in[3] spatial_shapes: static, hardcoded
    const float* W_off  = (const float*)d_in[4];
    const float* b_off  = (const float*)d_in[5];
    const float* W_attn = (const float*)d_in[6];
    const float* b_attn = (const float*)d_in[7];
    const float* W_v    = (const float*)d_in[8];
    const float* b_v    = (const float*)d_in[9];
    const float* W_out  = (const float*)d_in[10];
    const float* b_out  = (const float*)d_in[11];

    char* ws = (char*)d_ws;
    size_t off = 0;
    unsigned short* Vbf = (unsigned short*)(ws + off); off += (size_t)MV * 256 * 2;
    float* qout         = (float*)(ws + off);          off += (size_t)MQ * NQOUT * 4;
    float* outs         = (float*)(ws + off);          off += (size_t)MQ * 256 * 4;
    unsigned short* WtV = (unsigned short*)(ws + off); off += 256 * 256 * 2;
    unsigned short* WtQ = (unsigned short*)(ws + off); off += 384 * 256 * 2;
    unsigned short* WtO = (unsigned short*)(ws + off); off += 256 * 256 * 2;
    float* biasQ        = (float*)(ws + off);          off += 384 * 4;

    prep_kernel<<<384, 256, 0, stream>>>(W_v, W_off, W_attn, W_out, b_off, b_attn,
                                         WtV, WtQ, WtO, biasQ);

    // v = value @ W_v + b_v  -> bf16 (BM=64, BN=256: A read exactly once)
    gemm_kernel<1, 4, true, false><<<dim3((MV + 63) / 64, 1), 256, 0, stream>>>(
        value, WtV, b_v, nullptr, Vbf, MV, 256, 256);

    // [off | attn-logits] = query @ [W_off | W_attn] + [b_off | b_attn]
    gemm_kernel<2, 2, false, false><<<dim3((MQ + 127) / 128, 3), 256, 0, stream>>>(
        query, WtQ, biasQ, nullptr, qout, MQ, 256, NQOUT);

    sample_kernel<<<(BS * NQ * HEADS) / 16, 256, 0, stream>>>(Vbf, qout, rp, outs);

    // out = out_s @ W_out + b_out + query
    gemm_kernel<2, 2, false, true><<<dim3((MQ + 127) / 128, 2), 256, 0, stream>>>(
        outs, WtO, b_out, query, (float*)d_out, MQ, 256, 256);
}